// Round 5
// baseline (196.562 us; speedup 1.0000x reference)
//
#include <hip/hip_runtime.h>

#define HDIM 128

__device__ __forceinline__ ushort f2bf(float f) {
    unsigned x = __float_as_uint(f);
    unsigned r = (x + 0x7fffu + ((x >> 16) & 1u)) >> 16;   // RNE
    return (ushort)r;
}

// ---------- CSR build ----------
// zeroes deg[N] and the zero-row (row N) of xs
__global__ void zero_kernel(int* __restrict__ deg, int* __restrict__ xsN, int N) {
    int i = blockIdx.x * blockDim.x + threadIdx.x;
    if (i < N) deg[i] = 0;
    if (i < 64) xsN[i] = 0;      // 128 ushorts = 64 ints
}

__global__ void hist_kernel(const int* __restrict__ col, int* __restrict__ deg, int E) {
    int i = blockIdx.x * blockDim.x + threadIdx.x;
    if (i < E) atomicAdd(&deg[col[i]], 1);
}

// phase A: per-block (256-wide) exclusive scan of deg -> rowptr (partial), block sums
__global__ __launch_bounds__(256)
void scanA_kernel(const int* __restrict__ deg, int* __restrict__ rowptr,
                  int* __restrict__ blocksums, int N) {
    __shared__ int s[256];
    int t = threadIdx.x;
    int i = blockIdx.x * 256 + t;
    int v = (i < N) ? deg[i] : 0;
    s[t] = v;
    __syncthreads();
#pragma unroll
    for (int off = 1; off < 256; off <<= 1) {
        int u = (t >= off) ? s[t - off] : 0;
        __syncthreads();
        s[t] += u;
        __syncthreads();
    }
    if (i < N) rowptr[i] = s[t] - v;           // block-local exclusive
    if (t == 255) blocksums[blockIdx.x] = s[255];
}

// phase B: scan the block sums (one small block)
__global__ __launch_bounds__(128)
void scanB_kernel(int* __restrict__ blocksums, int* __restrict__ rowptr, int N, int NB) {
    __shared__ int s[128];
    int t = threadIdx.x;
    int v = (t < NB) ? blocksums[t] : 0;
    s[t] = v;
    __syncthreads();
#pragma unroll
    for (int off = 1; off < 128; off <<= 1) {
        int u = (t >= off) ? s[t - off] : 0;
        __syncthreads();
        s[t] += u;
        __syncthreads();
    }
    if (t < NB) blocksums[t] = s[t] - v;       // exclusive block offsets
    if (t == 127) rowptr[N] = s[127];          // total = E
}

// phase C: add offsets, emit cursor + dinv
__global__ void scanC_kernel(const int* __restrict__ deg, const int* __restrict__ blocksums,
                             int* __restrict__ rowptr, int* __restrict__ cursor,
                             float* __restrict__ dinv, int N) {
    int i = blockIdx.x * blockDim.x + threadIdx.x;
    if (i < N) {
        int p = rowptr[i] + blocksums[i >> 8];
        rowptr[i] = p;
        cursor[i] = p;
        dinv[i]   = rsqrtf((float)(deg[i] + 1));   // +1 self loop
    }
}

__global__ void fill_kernel(const int* __restrict__ row, const int* __restrict__ col,
                            int* __restrict__ cursor, int* __restrict__ esrc, int E) {
    int i = blockIdx.x * blockDim.x + threadIdx.x;
    if (i < E) {
        int pos = atomicAdd(&cursor[col[i]], 1);
        esrc[pos] = row[i];
    }
}

// ---------- GEMM + row scale: xs[n,:] = bf16((X[n,:] @ W) * dinv[n]) ----------
template<int K, int NPB>
__global__ void gemm_scale_kernel(const float* __restrict__ X, const float* __restrict__ W,
                                  const float* __restrict__ dinv,
                                  ushort* __restrict__ xs, int N) {
    __shared__ float xr[NPB * K];
    int t  = threadIdx.x;            // 128 threads
    int n0 = blockIdx.x * NPB;
    for (int i = t; i < NPB * K; i += 128)
        xr[i] = X[(long)n0 * K + i];
    __syncthreads();

    float acc[NPB];
#pragma unroll
    for (int m = 0; m < NPB; ++m) acc[m] = 0.f;

    for (int k = 0; k < K; ++k) {
        float w = W[k * HDIM + t];
#pragma unroll
        for (int m = 0; m < NPB; ++m) acc[m] += xr[m * K + k] * w;
    }

#pragma unroll
    for (int m = 0; m < NPB; ++m) {
        int n = n0 + m;
        if (n < N) {
            float v = acc[m] * dinv[n];
            float w = __shfl_xor(v, 1);          // neighbor column's value
            if (!(t & 1)) {
                ushort2 u;
                u.x = f2bf(v);
                u.y = f2bf(w);
                ((ushort2*)xs)[(long)n * 64 + (t >> 1)] = u;
            }
        }
    }
}

// ---------- gather: 4x16-lane groups, 4 rows (1KB) per load instruction ----------
// virtual entry list per node = [node, esrc[s..e)], padded with zero-row N.
// lane = 16*grp + sub; grp reads row idx[k+grp]; sub covers features 8*sub..8*sub+7.
template<bool FUSE_LN>
__global__ __launch_bounds__(256)
void gather_kernel(const int* __restrict__ rowptr, const int* __restrict__ esrc,
                   const ushort* __restrict__ xs, const float* __restrict__ dinv,
                   const float* __restrict__ bvec, float* __restrict__ out,
                   const float* __restrict__ lng, const float* __restrict__ lnb,
                   const float* __restrict__ Wq1, const float* __restrict__ bq1,
                   const float* __restrict__ Wq2, const float* __restrict__ bq2,
                   float* __restrict__ q1, float* __restrict__ q2, int N) {
    __shared__ float w1s[FUSE_LN ? HDIM * 5 : 1];
    __shared__ float w2s[FUSE_LN ? HDIM * 5 : 1];
    if (FUSE_LN) {
        for (int i = threadIdx.x; i < HDIM * 5; i += 256) {
            w1s[i] = Wq1[i];
            w2s[i] = Wq2[i];
        }
        __syncthreads();
    }

    int wave = threadIdx.x >> 6;
    int lane = threadIdx.x & 63;
    int node = blockIdx.x * 4 + wave;
    if (node >= N) return;

    int grp = lane >> 4;      // 0..3
    int sub = lane & 15;      // feature block

    float acc[8];
#pragma unroll
    for (int j = 0; j < 8; ++j) acc[j] = 0.f;

    int s = rowptr[node];
    int e = rowptr[node + 1];
    int total = e - s + 1;    // + self

    for (int base = 0; base < total; base += 64) {
        int p = base + lane;
        int idx = N;                              // zero row
        if (p == 0)           idx = node;         // self loop
        else if (p < total)   idx = esrc[s + p - 1];

        int m = total - base;
        if (m > 64) m = 64;
        for (int k = 0; k < m; k += 8) {
            int r0 = __shfl(idx, k + grp);
            int r1 = __shfl(idx, k + 4 + grp);
            uint4 u0 = *((const uint4*)(xs + ((long)r0 << 7)) + sub);
            uint4 u1 = *((const uint4*)(xs + ((long)r1 << 7)) + sub);
            acc[0] += __uint_as_float(u0.x << 16);
            acc[1] += __uint_as_float(u0.x & 0xffff0000u);
            acc[2] += __uint_as_float(u0.y << 16);
            acc[3] += __uint_as_float(u0.y & 0xffff0000u);
            acc[4] += __uint_as_float(u0.z << 16);
            acc[5] += __uint_as_float(u0.z & 0xffff0000u);
            acc[6] += __uint_as_float(u0.w << 16);
            acc[7] += __uint_as_float(u0.w & 0xffff0000u);
            acc[0] += __uint_as_float(u1.x << 16);
            acc[1] += __uint_as_float(u1.x & 0xffff0000u);
            acc[2] += __uint_as_float(u1.y << 16);
            acc[3] += __uint_as_float(u1.y & 0xffff0000u);
            acc[4] += __uint_as_float(u1.z << 16);
            acc[5] += __uint_as_float(u1.z & 0xffff0000u);
            acc[6] += __uint_as_float(u1.w << 16);
            acc[7] += __uint_as_float(u1.w & 0xffff0000u);
        }
    }

    // combine the 4 groups' partial sums (lanes with equal sub share features)
#pragma unroll
    for (int j = 0; j < 8; ++j) {
        acc[j] += __shfl_xor(acc[j], 16);
        acc[j] += __shfl_xor(acc[j], 32);
    }

    float di = dinv[node];
    const float4* bv = (const float4*)bvec;
    float4 b0 = bv[sub * 2], b1 = bv[sub * 2 + 1];
    float v[8];
    v[0] = acc[0] * di + b0.x;  v[1] = acc[1] * di + b0.y;
    v[2] = acc[2] * di + b0.z;  v[3] = acc[3] * di + b0.w;
    v[4] = acc[4] * di + b1.x;  v[5] = acc[5] * di + b1.y;
    v[6] = acc[6] * di + b1.z;  v[7] = acc[7] * di + b1.w;
#pragma unroll
    for (int j = 0; j < 8; ++j) v[j] = v[j] > 0.f ? v[j] : 0.f;

    if (!FUSE_LN) {
        if (grp == 0) {
            float4* op = (float4*)(out + ((long)node << 7)) + sub * 2;
            op[0] = make_float4(v[0], v[1], v[2], v[3]);
            op[1] = make_float4(v[4], v[5], v[6], v[7]);
        }
        return;
    }

    // ---- LayerNorm (reduce across sub: width-16 butterfly) ----
    float sm = 0.f, ss = 0.f;
#pragma unroll
    for (int j = 0; j < 8; ++j) { sm += v[j]; ss += v[j] * v[j]; }
#pragma unroll
    for (int off = 8; off >= 1; off >>= 1) {
        sm += __shfl_xor(sm, off);
        ss += __shfl_xor(ss, off);
    }
    float mu  = sm * (1.0f / HDIM);
    float var = ss * (1.0f / HDIM) - mu * mu;
    float rs  = rsqrtf(var + 1e-5f);

    const float4* lg = (const float4*)lng;
    const float4* lb = (const float4*)lnb;
    float4 g0 = lg[sub * 2], g1 = lg[sub * 2 + 1];
    float4 c0 = lb[sub * 2], c1 = lb[sub * 2 + 1];
    float h[8];
    h[0] = (v[0] - mu) * rs * g0.x + c0.x;  h[1] = (v[1] - mu) * rs * g0.y + c0.y;
    h[2] = (v[2] - mu) * rs * g0.z + c0.z;  h[3] = (v[3] - mu) * rs * g0.w + c0.w;
    h[4] = (v[4] - mu) * rs * g1.x + c1.x;  h[5] = (v[5] - mu) * rs * g1.y + c1.y;
    h[6] = (v[6] - mu) * rs * g1.z + c1.z;  h[7] = (v[7] - mu) * rs * g1.w + c1.w;

    if (grp == 0) {
        float4* op = (float4*)(out + ((long)node << 7)) + sub * 2;
        op[0] = make_float4(h[0], h[1], h[2], h[3]);
        op[1] = make_float4(h[4], h[5], h[6], h[7]);
    }

    // ---- Q heads ----
    float p1[5], p2[5];
#pragma unroll
    for (int j = 0; j < 5; ++j) { p1[j] = 0.f; p2[j] = 0.f; }
#pragma unroll
    for (int jj = 0; jj < 8; ++jj) {
        int f = sub * 8 + jj;
#pragma unroll
        for (int j = 0; j < 5; ++j) {
            p1[j] += h[jj] * w1s[f * 5 + j];
            p2[j] += h[jj] * w2s[f * 5 + j];
        }
    }
#pragma unroll
    for (int off = 8; off >= 1; off >>= 1) {
#pragma unroll
        for (int j = 0; j < 5; ++j) {
            p1[j] += __shfl_xor(p1[j], off);
            p2[j] += __shfl_xor(p2[j], off);
        }
    }
    if (lane == 0) {
#pragma unroll
        for (int j = 0; j < 5; ++j) {
            q1[(long)node * 5 + j] = p1[j] + bq1[j];
            q2[(long)node * 5 + j] = p2[j] + bq2[j];
        }
    }
}

extern "C" void kernel_launch(void* const* d_in, const int* in_sizes, int n_in,
                              void* d_out, int out_size, void* d_ws, size_t ws_size,
                              hipStream_t stream) {
    const float* x    = (const float*)d_in[0];
    const int*   ei   = (const int*)d_in[1];
    const float* W1   = (const float*)d_in[2];
    const float* b1   = (const float*)d_in[3];
    const float* W2   = (const float*)d_in[4];
    const float* b2   = (const float*)d_in[5];
    const float* lng  = (const float*)d_in[6];
    const float* lnb  = (const float*)d_in[7];
    const float* Wq1  = (const float*)d_in[8];
    const float* bq1  = (const float*)d_in[9];
    const float* Wq2  = (const float*)d_in[10];
    const float* bq2  = (const float*)d_in[11];

    const int D = 64;
    const int N = in_sizes[0] / D;        // 32768
    const int E = in_sizes[1] / 2;        // 524288
    const int* row = ei;
    const int* col = ei + E;

    // workspace layout (xs has N+1 rows; row N is the zero row)
    ushort* xs     = (ushort*)d_ws;                          // bf16  (N+1)*128
    float*  B1     = (float*)(xs + (long)(N + 1) * HDIM);    // f32   N*128 (h1)
    float*  dinv   = B1 + (long)N * HDIM;                    // N f
    int*    deg    = (int*)(dinv + N);                       // N i
    int*    rowptr = deg + N;                                // N+1 i
    int*    cursor = rowptr + N + 1;                         // N i
    int*    esrc   = cursor + N;                             // E i
    int*    bsums  = esrc + E;                               // 128 i

    float* q1   = (float*)d_out;
    float* q2   = q1 + (long)N * 5;
    float* hout = q2 + (long)N * 5;

    const int NB = (N + 255) / 256;       // scan blocks (128)

    // ---- CSR build ----
    zero_kernel<<<NB, 256, 0, stream>>>(deg, (int*)(xs + (long)N * HDIM), N);
    hist_kernel<<<(E + 255) / 256, 256, 0, stream>>>(col, deg, E);
    scanA_kernel<<<NB, 256, 0, stream>>>(deg, rowptr, bsums, N);
    scanB_kernel<<<1, 128, 0, stream>>>(bsums, rowptr, N, NB);
    scanC_kernel<<<NB, 256, 0, stream>>>(deg, bsums, rowptr, cursor, dinv, N);
    fill_kernel<<<(E + 255) / 256, 256, 0, stream>>>(row, col, cursor, esrc, E);

    // ---- layer 1: gemm -> xs(bf16), gather -> B1(f32) ----
    gemm_scale_kernel<64, 8><<<(N + 7) / 8, 128, 0, stream>>>(x, W1, dinv, xs, N);
    gather_kernel<false><<<(N + 3) / 4, 256, 0, stream>>>(
        rowptr, esrc, xs, dinv, b1, B1,
        nullptr, nullptr, nullptr, nullptr, nullptr, nullptr, nullptr, nullptr, N);

    // ---- layer 2: gemm -> xs(bf16), gather fused with LN + heads ----
    gemm_scale_kernel<128, 8><<<(N + 7) / 8, 128, 0, stream>>>(B1, W2, dinv, xs, N);
    gather_kernel<true><<<(N + 3) / 4, 256, 0, stream>>>(
        rowptr, esrc, xs, dinv, b2, hout,
        lng, lnb, Wq1, bq1, Wq2, bq2, q1, q2, N);
}

// Round 6
// 182.285 us; speedup vs baseline: 1.0783x; 1.0783x over previous
//
#include <hip/hip_runtime.h>

#define HDIM 128

__device__ __forceinline__ ushort f2bf(float f) {
    unsigned x = __float_as_uint(f);
    unsigned r = (x + 0x7fffu + ((x >> 16) & 1u)) >> 16;   // RNE
    return (ushort)r;
}

// ---------- CSR build ----------
// zeroes deg[N] and the zero-row (row N) of xs
__global__ void zero_kernel(int* __restrict__ deg, int* __restrict__ xsN, int N) {
    int i = blockIdx.x * blockDim.x + threadIdx.x;
    if (i < N) deg[i] = 0;
    if (i < 64) xsN[i] = 0;      // 128 ushorts = 64 ints
}

__global__ void hist_kernel(const int* __restrict__ col, int* __restrict__ deg, int E) {
    int i = blockIdx.x * blockDim.x + threadIdx.x;
    if (i < E) atomicAdd(&deg[col[i]], 1);
}

// phase A: per-block (256-wide) exclusive scan of deg -> rowptr (partial), block sums
__global__ __launch_bounds__(256)
void scanA_kernel(const int* __restrict__ deg, int* __restrict__ rowptr,
                  int* __restrict__ blocksums, int N) {
    __shared__ int s[256];
    int t = threadIdx.x;
    int i = blockIdx.x * 256 + t;
    int v = (i < N) ? deg[i] : 0;
    s[t] = v;
    __syncthreads();
#pragma unroll
    for (int off = 1; off < 256; off <<= 1) {
        int u = (t >= off) ? s[t - off] : 0;
        __syncthreads();
        s[t] += u;
        __syncthreads();
    }
    if (i < N) rowptr[i] = s[t] - v;           // block-local exclusive
    if (t == 255) blocksums[blockIdx.x] = s[255];
}

// phase B: scan the block sums (one small block)
__global__ __launch_bounds__(128)
void scanB_kernel(int* __restrict__ blocksums, int* __restrict__ rowptr, int N, int NB) {
    __shared__ int s[128];
    int t = threadIdx.x;
    int v = (t < NB) ? blocksums[t] : 0;
    s[t] = v;
    __syncthreads();
#pragma unroll
    for (int off = 1; off < 128; off <<= 1) {
        int u = (t >= off) ? s[t - off] : 0;
        __syncthreads();
        s[t] += u;
        __syncthreads();
    }
    if (t < NB) blocksums[t] = s[t] - v;       // exclusive block offsets
    if (t == 127) rowptr[N] = s[127];          // total = E
}

// phase C: add offsets, emit cursor + dinv
__global__ void scanC_kernel(const int* __restrict__ deg, const int* __restrict__ blocksums,
                             int* __restrict__ rowptr, int* __restrict__ cursor,
                             float* __restrict__ dinv, int N) {
    int i = blockIdx.x * blockDim.x + threadIdx.x;
    if (i < N) {
        int p = rowptr[i] + blocksums[i >> 8];
        rowptr[i] = p;
        cursor[i] = p;
        dinv[i]   = rsqrtf((float)(deg[i] + 1));   // +1 self loop
    }
}

__global__ void fill_kernel(const int* __restrict__ row, const int* __restrict__ col,
                            int* __restrict__ cursor, int* __restrict__ esrc, int E) {
    int i = blockIdx.x * blockDim.x + threadIdx.x;
    if (i < E) {
        int pos = atomicAdd(&cursor[col[i]], 1);
        esrc[pos] = row[i];
    }
}

// ---------- GEMM + row scale: xs[n,:] = bf16((X[n,:] @ W) * dinv[n]) ----------
template<int K, int NPB>
__global__ void gemm_scale_kernel(const float* __restrict__ X, const float* __restrict__ W,
                                  const float* __restrict__ dinv,
                                  ushort* __restrict__ xs, int N) {
    __shared__ float xr[NPB * K];
    int t  = threadIdx.x;            // 128 threads
    int n0 = blockIdx.x * NPB;
    for (int i = t; i < NPB * K; i += 128)
        xr[i] = X[(long)n0 * K + i];
    __syncthreads();

    float acc[NPB];
#pragma unroll
    for (int m = 0; m < NPB; ++m) acc[m] = 0.f;

    for (int k = 0; k < K; ++k) {
        float w = W[k * HDIM + t];
#pragma unroll
        for (int m = 0; m < NPB; ++m) acc[m] += xr[m * K + k] * w;
    }

#pragma unroll
    for (int m = 0; m < NPB; ++m) {
        int n = n0 + m;
        if (n < N) {
            float v = acc[m] * dinv[n];
            float w = __shfl_xor(v, 1);          // neighbor column's value
            if (!(t & 1)) {
                ushort2 u;
                u.x = f2bf(v);
                u.y = f2bf(w);
                ((ushort2*)xs)[(long)n * 64 + (t >> 1)] = u;
            }
        }
    }
}

// ---------- gather: one wave per node, one coalesced 256B row per load, 8-deep ----------
// virtual entry list per node = [node, esrc[s..e)], padded with zero-row N (branch-free).
template<bool FUSE_LN>
__global__ __launch_bounds__(256)
void gather_kernel(const int* __restrict__ rowptr, const int* __restrict__ esrc,
                   const ushort* __restrict__ xs, const float* __restrict__ dinv,
                   const float* __restrict__ bvec, float* __restrict__ out,
                   const float* __restrict__ lng, const float* __restrict__ lnb,
                   const float* __restrict__ Wq1, const float* __restrict__ bq1,
                   const float* __restrict__ Wq2, const float* __restrict__ bq2,
                   float* __restrict__ q1, float* __restrict__ q2, int N) {
    __shared__ float w1s[FUSE_LN ? HDIM * 5 : 1];
    __shared__ float w2s[FUSE_LN ? HDIM * 5 : 1];
    if (FUSE_LN) {
        for (int i = threadIdx.x; i < HDIM * 5; i += 256) {
            w1s[i] = Wq1[i];
            w2s[i] = Wq2[i];
        }
        __syncthreads();
    }

    int wave = threadIdx.x >> 6;
    int lane = threadIdx.x & 63;
    int node = blockIdx.x * 4 + wave;
    if (node >= N) return;

    const unsigned* rows = (const unsigned*)xs;   // 64 x 4B per row

    float ax = 0.f, ay = 0.f;

    int s = rowptr[node];
    int e = rowptr[node + 1];
    int total = e - s + 1;    // + self

    for (int base = 0; base < total; base += 64) {
        int p = base + lane;
        int idx = N;                              // zero row (pad)
        if (p == 0)           idx = node;         // self loop
        else if (p < total)   idx = esrc[s + p - 1];

        int m = total - base;
        if (m > 64) m = 64;
        // 8-deep unrolled; lanes k..k+7 always < 64, padded lanes hold idx=N
        for (int k = 0; k < m; k += 8) {
            int r[8];
#pragma unroll
            for (int i = 0; i < 8; ++i) r[i] = __shfl(idx, k + i);
            unsigned u[8];
#pragma unroll
            for (int i = 0; i < 8; ++i) u[i] = rows[((long)r[i] << 6) + lane];
#pragma unroll
            for (int i = 0; i < 8; ++i) {
                ax += __uint_as_float(u[i] << 16);
                ay += __uint_as_float(u[i] & 0xffff0000u);
            }
        }
    }

    float di = dinv[node];
    int d0 = 2 * lane;
    float vx = ax * di + bvec[d0];
    float vy = ay * di + bvec[d0 + 1];
    vx = vx > 0.f ? vx : 0.f;
    vy = vy > 0.f ? vy : 0.f;

    if (!FUSE_LN) {
        ((float2*)(out + ((long)node << 7)))[lane] = make_float2(vx, vy);
        return;
    }

    // ---- LayerNorm ----
    float sm = vx + vy, ss = vx * vx + vy * vy;
#pragma unroll
    for (int off = 32; off >= 1; off >>= 1) {
        sm += __shfl_xor(sm, off);
        ss += __shfl_xor(ss, off);
    }
    float mu  = sm * (1.0f / HDIM);
    float var = ss * (1.0f / HDIM) - mu * mu;
    float rs  = rsqrtf(var + 1e-5f);

    float h0 = (vx - mu) * rs * lng[d0]     + lnb[d0];
    float h1 = (vy - mu) * rs * lng[d0 + 1] + lnb[d0 + 1];
    ((float2*)(out + ((long)node << 7)))[lane] = make_float2(h0, h1);

    // ---- Q heads ----
    float p1[5], p2[5];
#pragma unroll
    for (int j = 0; j < 5; ++j) {
        p1[j] = h0 * w1s[d0 * 5 + j] + h1 * w1s[(d0 + 1) * 5 + j];
        p2[j] = h0 * w2s[d0 * 5 + j] + h1 * w2s[(d0 + 1) * 5 + j];
    }
#pragma unroll
    for (int off = 32; off >= 1; off >>= 1) {
#pragma unroll
        for (int j = 0; j < 5; ++j) {
            p1[j] += __shfl_xor(p1[j], off);
            p2[j] += __shfl_xor(p2[j], off);
        }
    }
    if (lane == 0) {
#pragma unroll
        for (int j = 0; j < 5; ++j) {
            q1[(long)node * 5 + j] = p1[j] + bq1[j];
            q2[(long)node * 5 + j] = p2[j] + bq2[j];
        }
    }
}

extern "C" void kernel_launch(void* const* d_in, const int* in_sizes, int n_in,
                              void* d_out, int out_size, void* d_ws, size_t ws_size,
                              hipStream_t stream) {
    const float* x    = (const float*)d_in[0];
    const int*   ei   = (const int*)d_in[1];
    const float* W1   = (const float*)d_in[2];
    const float* b1   = (const float*)d_in[3];
    const float* W2   = (const float*)d_in[4];
    const float* b2   = (const float*)d_in[5];
    const float* lng  = (const float*)d_in[6];
    const float* lnb  = (const float*)d_in[7];
    const float* Wq1  = (const float*)d_in[8];
    const float* bq1  = (const float*)d_in[9];
    const float* Wq2  = (const float*)d_in[10];
    const float* bq2  = (const float*)d_in[11];

    const int D = 64;
    const int N = in_sizes[0] / D;        // 32768
    const int E = in_sizes[1] / 2;        // 524288
    const int* row = ei;
    const int* col = ei + E;

    // workspace layout (xs has N+1 rows; row N is the zero row)
    ushort* xs     = (ushort*)d_ws;                          // bf16  (N+1)*128
    float*  B1     = (float*)(xs + (long)(N + 1) * HDIM);    // f32   N*128 (h1)
    float*  dinv   = B1 + (long)N * HDIM;                    // N f
    int*    deg    = (int*)(dinv + N);                       // N i
    int*    rowptr = deg + N;                                // N+1 i
    int*    cursor = rowptr + N + 1;                         // N i
    int*    esrc   = cursor + N;                             // E i
    int*    bsums  = esrc + E;                               // 128 i

    float* q1   = (float*)d_out;
    float* q2   = q1 + (long)N * 5;
    float* hout = q2 + (long)N * 5;

    const int NB = (N + 255) / 256;       // scan blocks (128)

    // ---- CSR build ----
    zero_kernel<<<NB, 256, 0, stream>>>(deg, (int*)(xs + (long)N * HDIM), N);
    hist_kernel<<<(E + 255) / 256, 256, 0, stream>>>(col, deg, E);
    scanA_kernel<<<NB, 256, 0, stream>>>(deg, rowptr, bsums, N);
    scanB_kernel<<<1, 128, 0, stream>>>(bsums, rowptr, N, NB);
    scanC_kernel<<<NB, 256, 0, stream>>>(deg, bsums, rowptr, cursor, dinv, N);
    fill_kernel<<<(E + 255) / 256, 256, 0, stream>>>(row, col, cursor, esrc, E);

    // ---- layer 1: gemm -> xs(bf16), gather -> B1(f32) ----
    gemm_scale_kernel<64, 8><<<(N + 7) / 8, 128, 0, stream>>>(x, W1, dinv, xs, N);
    gather_kernel<false><<<(N + 3) / 4, 256, 0, stream>>>(
        rowptr, esrc, xs, dinv, b1, B1,
        nullptr, nullptr, nullptr, nullptr, nullptr, nullptr, nullptr, nullptr, N);

    // ---- layer 2: gemm -> xs(bf16), gather fused with LN + heads ----
    gemm_scale_kernel<128, 8><<<(N + 7) / 8, 128, 0, stream>>>(B1, W2, dinv, xs, N);
    gather_kernel<true><<<(N + 3) / 4, 256, 0, stream>>>(
        rowptr, esrc, xs, dinv, b2, hout,
        lng, lnb, Wq1, bq1, Wq2, bq2, q1, q2, N);
}